// Round 8
// baseline (3668.730 us; speedup 1.0000x reference)
//
#include <hip/hip_runtime.h>

#define HDIM  128
#define G3    384
#define RPB   32
#define NTHR  512
#define NSTEP 256
#define NOUT  33
#define BROWS 8192
#define NBLK  (BROWS / RPB)      // 256 blocks -> 1 per CU
#define LOGP_ELEMS 69206016LL    // 8192*256*33
#define PRED_LD 34

typedef _Float16 half8 __attribute__((ext_vector_type(8)));
typedef float    f32x4 __attribute__((ext_vector_type(4)));

// ---------------- ws layout ----------------
#define WP_BYTES  294912         // 3 mats x 24 nt x 4 kc x 1024 B (fp16 single split)
#define FP_BYTES  24576          // fc: 3 nt x 4 kc x 2 s x 1024 B
// T1: 33 rows x 384 f32 (row 32 = the t==0 / SOS,dur=0 row)

__device__ __forceinline__ float sigf(float x) { return 1.0f / (1.0f + __expf(-x)); }
__device__ __forceinline__ float tanh_fast(float x) { return 1.0f - 2.0f / (__expf(2.0f*x) + 1.0f); }

// ---------------- prep: gi0 tables (fp32), 33 rows ----------------
__global__ void prep_kernel(const float* __restrict__ emb, const float* __restrict__ wih0,
                            const float* __restrict__ bih0, float* __restrict__ T1) {
    int a = blockIdx.x;          // 0..31
    int g = threadIdx.x;         // 0..383
    const float* e = emb + a * 127;
    const float* w = wih0 + g * HDIM;
    float s = bih0[g];
    for (int k = 0; k < 127; ++k) s += e[k] * w[k];
    T1[a * G3 + g] = s + w[127];           // dur = 1
    if (a == 0) T1[32 * G3 + g] = s;       // t==0 row: act=0, dur=0
}

// ---------------- prep: pack weights (fp16 single split) + fc (2-split) ----------------
// lane holds B[g = nt*16 + (lane&15)][k = kc*32 + (lane>>4)*8 + e]
__global__ void prep_pack(const float* __restrict__ whh0, const float* __restrict__ wih1,
                          const float* __restrict__ whh1, const float* __restrict__ fcw,
                          half8* __restrict__ WP) {
    int b = blockIdx.x;            // 0..74 : 0-71 weight tiles, 72-74 fc
    int tid  = threadIdx.x;        // 256
    int lane = tid & 63;
    int kc   = tid >> 6;
    bool isfc = (b >= 72);
    if (!isfc) {
        int mat = b / 24, nt = b % 24;
        const float* W = (mat == 0) ? whh0 : (mat == 1) ? wih1 : whh1;
        int g = nt * 16 + (lane & 15);
        int k = kc * 32 + (lane >> 4) * 8;
        half8 v1;
#pragma unroll
        for (int e = 0; e < 8; ++e) v1[e] = (_Float16)W[g * HDIM + k + e];
        WP[(size_t)(((mat * 24 + nt) * 4 + kc)) * 64 + lane] = v1;
    } else {
        int nt = b - 72;
        int g = nt * 16 + (lane & 15);
        int k = kc * 32 + (lane >> 4) * 8;
        half8 v1, v2;
#pragma unroll
        for (int e = 0; e < 8; ++e) {
            float x = (g >= NOUT) ? 0.0f : fcw[g * HDIM + k + e];
            _Float16 s1 = (_Float16)x;
            v1[e] = s1; v2[e] = (_Float16)(x - (float)s1);
        }
        size_t base = (size_t)(WP_BYTES / 1024 + (nt * 4 + kc) * 2) * 64 + lane;
        WP[base]      = v1;
        WP[base + 64] = v2;
    }
}

// ---------------- main decoder: register-streamed B tiles ----------------
__launch_bounds__(NTHR, 2)
__global__ void decoder_kernel(const float* __restrict__ hid,
                               const float* __restrict__ T1,
                               const char* __restrict__ Bpg,
                               const float* __restrict__ bhh0,
                               const float* __restrict__ bih1, const float* __restrict__ bhh1,
                               const float* __restrict__ fcb,
                               float* __restrict__ out) {
    __shared__ char  hs0[16384];     // h0 splits: [32][256B] swz, split1 at +8192
    __shared__ char  hs1[16384];
    __shared__ float preds[RPB * PRED_LD];
    __shared__ int   acts[RPB];

    const int tid  = threadIdx.x;
    const int row0 = blockIdx.x * RPB;
    float* lp = out;
    float* pp = out + LOGP_ELEMS;

    const int lane  = tid & 63;
    const int w     = tid >> 6;      // wave 0..7
    const int col   = lane & 15;
    const int q     = lane >> 4;
    const int akoff = q * 16;        // A-frag byte offset within 64B k-chunk
    const int j     = w * 16 + col;  // gate/hidden column owned by this lane

    // hoisted per-lane biases
    const float bG0 = bhh0[j], bG1 = bhh0[128 + j], bG2 = bhh0[256 + j];
    const float bH0 = bhh1[j], bH1 = bhh1[128 + j], bH2 = bhh1[256 + j];
    const float bI0 = bih1[j], bI1 = bih1[128 + j], bI2 = bih1[256 + j];

    // fc weights -> 16 VGPR (2-split); waves 0-5 active: fMt = w/3, fnt = w%3
    const int fnt = w % 3, fMt = (w / 3) & 1;
    const int fo  = fnt * 16 + col;
    const float fbias = (fo < NOUT) ? fcb[fo] : 0.0f;
    half8 fcr[4][2];
#pragma unroll
    for (int kc = 0; kc < 4; ++kc)
#pragma unroll
        for (int s = 0; s < 2; ++s)
            fcr[kc][s] = *(const half8*)(Bpg + WP_BYTES +
                (size_t)(((fnt * 4 + kc) * 2 + s) * 1024) + lane * 16);

    if (tid < RPB) acts[tid] = 32;   // t==0 -> T1 row 32

    // ---- init h0/h1 -> VGPRs + fp16 2-splits to LDS ----
    float h0v[2][4], h1v[2][4];
#pragma unroll
    for (int Mt = 0; Mt < 2; ++Mt)
#pragma unroll
        for (int i = 0; i < 4; ++i) {
            int row = Mt * 16 + q * 4 + i;
            float v0 = hid[(size_t)(row0 + row) * HDIM + j];
            float v1 = hid[(size_t)BROWS * HDIM + (size_t)(row0 + row) * HDIM + j];
            h0v[Mt][i] = v0; h1v[Mt][i] = v1;
            int off = (row * 256 + j * 2) ^ ((row & 7) << 4);
            _Float16 s1 = (_Float16)v0, s2 = (_Float16)(v0 - (float)s1);
            *(_Float16*)(hs0 + off) = s1;
            *(_Float16*)(hs0 + 8192 + off) = s2;
            s1 = (_Float16)v1; s2 = (_Float16)(v1 - (float)s1);
            *(_Float16*)(hs1 + off) = s1;
            *(_Float16*)(hs1 + 8192 + off) = s2;
        }
    __syncthreads();

#define LGKM0() asm volatile("s_waitcnt lgkmcnt(0)" ::: "memory")
#define BAR()   __builtin_amdgcn_s_barrier()
#define MFMA(a, b, c) __builtin_amdgcn_mfma_f32_16x16x32_f16((a), (b), (c), 0, 0, 0)
    // B tile (mat, c): kc = c/3, ty = c%3, nt = ty*8 + w
#define LDB(mat_, c_) (*(const half8*)(Bpg + \
        (size_t)(((((mat_) * 24 + ((c_) % 3) * 8 + w)) * 4 + (c_) / 3) * 1024) + lane * 16))

#pragma unroll 1
    for (int t = 0; t < NSTEP; ++t) {
        // ---- T-table gather (acts from prev step; hides under phase A) ----
        float gi[3][2][4];
#pragma unroll
        for (int Mt = 0; Mt < 2; ++Mt)
#pragma unroll
            for (int i = 0; i < 4; ++i) {
                const float* tab = T1 + acts[Mt * 16 + q * 4 + i] * G3;
                gi[0][Mt][i] = tab[j];
                gi[1][Mt][i] = tab[128 + j];
                gi[2][Mt][i] = tab[256 + j];
            }

        // ---- issue phase-A B loads (register stream, compiler-counted waits) ----
        half8 B0[12], B1[12];
#pragma unroll
        for (int c = 0; c < 12; ++c) B0[c] = LDB(0, c);   // whh0
#pragma unroll
        for (int c = 0; c < 12; ++c) B1[c] = LDB(2, c);   // whh1

        // ---- phase A: gh0 = h0.whh0^T (+b), gh1 = h1.whh1^T (+b) ----
        f32x4 g0[3][2], ah[3][2];
        {
            f32x4 v0 = {bG0, bG0, bG0, bG0}, v1 = {bG1, bG1, bG1, bG1}, v2 = {bG2, bG2, bG2, bG2};
            g0[0][0] = v0; g0[0][1] = v0; g0[1][0] = v1; g0[1][1] = v1; g0[2][0] = v2; g0[2][1] = v2;
            f32x4 u0 = {bH0, bH0, bH0, bH0}, u1 = {bH1, bH1, bH1, bH1}, u2 = {bH2, bH2, bH2, bH2};
            ah[0][0] = u0; ah[0][1] = u0; ah[1][0] = u1; ah[1][1] = u1; ah[2][0] = u2; ah[2][1] = u2;
        }
#pragma unroll
        for (int kc = 0; kc < 4; ++kc) {
            half8 a1[2], a2[2];
#pragma unroll
            for (int Mt = 0; Mt < 2; ++Mt) {
                int row = Mt * 16 + col;
                int off = (row * 256 + kc * 64 + akoff) ^ ((row & 7) << 4);
                a1[Mt] = *(const half8*)(hs0 + off);
                a2[Mt] = *(const half8*)(hs0 + 8192 + off);
            }
#pragma unroll
            for (int ty = 0; ty < 3; ++ty) {
#pragma unroll
                for (int Mt = 0; Mt < 2; ++Mt) {
                    g0[ty][Mt] = MFMA(a1[Mt], B0[kc * 3 + ty], g0[ty][Mt]);
                    g0[ty][Mt] = MFMA(a2[Mt], B0[kc * 3 + ty], g0[ty][Mt]);
                }
            }
        }
#pragma unroll
        for (int kc = 0; kc < 4; ++kc) {
            half8 a1[2], a2[2];
#pragma unroll
            for (int Mt = 0; Mt < 2; ++Mt) {
                int row = Mt * 16 + col;
                int off = (row * 256 + kc * 64 + akoff) ^ ((row & 7) << 4);
                a1[Mt] = *(const half8*)(hs1 + off);
                a2[Mt] = *(const half8*)(hs1 + 8192 + off);
            }
#pragma unroll
            for (int ty = 0; ty < 3; ++ty) {
#pragma unroll
                for (int Mt = 0; Mt < 2; ++Mt) {
                    ah[ty][Mt] = MFMA(a1[Mt], B1[kc * 3 + ty], ah[ty][Mt]);
                    ah[ty][Mt] = MFMA(a2[Mt], B1[kc * 3 + ty], ah[ty][Mt]);
                }
            }
        }

        // ---- issue phase-B (gi1 / wih1) loads before BAR1: hide under gates0 ----
        half8 B2[12];
#pragma unroll
        for (int c = 0; c < 12; ++c) B2[c] = LDB(1, c);

        LGKM0(); BAR();   // BAR1: all hs0/hs1 reads done before rewrites

        // ---- gates0: h0_new -> VGPR + hs0 splits ----
#pragma unroll
        for (int Mt = 0; Mt < 2; ++Mt)
#pragma unroll
            for (int i = 0; i < 4; ++i) {
                float rg = sigf(gi[0][Mt][i] + g0[0][Mt][i]);
                float zg = sigf(gi[1][Mt][i] + g0[1][Mt][i]);
                float ng = tanh_fast(gi[2][Mt][i] + rg * g0[2][Mt][i]);
                float hnew = (1.0f - zg) * ng + zg * h0v[Mt][i];
                h0v[Mt][i] = hnew;
                int row = Mt * 16 + q * 4 + i;
                int off = (row * 256 + j * 2) ^ ((row & 7) << 4);
                _Float16 s1 = (_Float16)hnew, s2 = (_Float16)(hnew - (float)s1);
                *(_Float16*)(hs0 + off) = s1;
                *(_Float16*)(hs0 + 8192 + off) = s2;
            }
        LGKM0(); BAR();   // BAR2: hs0_new visible

        // ---- phase B: gi1 = h0_new.wih1^T (+b) ----
        f32x4 ai[3][2];
        {
            f32x4 v0 = {bI0, bI0, bI0, bI0}, v1 = {bI1, bI1, bI1, bI1}, v2 = {bI2, bI2, bI2, bI2};
            ai[0][0] = v0; ai[0][1] = v0; ai[1][0] = v1; ai[1][1] = v1; ai[2][0] = v2; ai[2][1] = v2;
        }
#pragma unroll
        for (int kc = 0; kc < 4; ++kc) {
            half8 a1[2], a2[2];
#pragma unroll
            for (int Mt = 0; Mt < 2; ++Mt) {
                int row = Mt * 16 + col;
                int off = (row * 256 + kc * 64 + akoff) ^ ((row & 7) << 4);
                a1[Mt] = *(const half8*)(hs0 + off);
                a2[Mt] = *(const half8*)(hs0 + 8192 + off);
            }
#pragma unroll
            for (int ty = 0; ty < 3; ++ty) {
#pragma unroll
                for (int Mt = 0; Mt < 2; ++Mt) {
                    ai[ty][Mt] = MFMA(a1[Mt], B2[kc * 3 + ty], ai[ty][Mt]);
                    ai[ty][Mt] = MFMA(a2[Mt], B2[kc * 3 + ty], ai[ty][Mt]);
                }
            }
        }

        // ---- gates1: h1_new -> VGPR + hs1 splits (hs1 reads fenced by BAR1) ----
#pragma unroll
        for (int Mt = 0; Mt < 2; ++Mt)
#pragma unroll
            for (int i = 0; i < 4; ++i) {
                float rg = sigf(ai[0][Mt][i] + ah[0][Mt][i]);
                float zg = sigf(ai[1][Mt][i] + ah[1][Mt][i]);
                float ng = tanh_fast(ai[2][Mt][i] + rg * ah[2][Mt][i]);
                float hnew = (1.0f - zg) * ng + zg * h1v[Mt][i];
                h1v[Mt][i] = hnew;
                int row = Mt * 16 + q * 4 + i;
                int off = (row * 256 + j * 2) ^ ((row & 7) << 4);
                _Float16 s1 = (_Float16)hnew, s2 = (_Float16)(hnew - (float)s1);
                *(_Float16*)(hs1 + off) = s1;
                *(_Float16*)(hs1 + 8192 + off) = s2;
            }
        LGKM0(); BAR();   // BAR3: hs1_new visible

        // ---- fc: preds = h1_new.fc_w^T + fc_b (waves 0-5, B in VGPRs) ----
        if (w < 6) {
            f32x4 acc = {fbias, fbias, fbias, fbias};
#pragma unroll
            for (int kc = 0; kc < 4; ++kc) {
                int row = fMt * 16 + col;
                int off = (row * 256 + kc * 64 + akoff) ^ ((row & 7) << 4);
                half8 a1 = *(const half8*)(hs1 + off);
                half8 a2 = *(const half8*)(hs1 + 8192 + off);
                acc = MFMA(a1, fcr[kc][0], acc);
                acc = MFMA(a2, fcr[kc][0], acc);
                acc = MFMA(a1, fcr[kc][1], acc);
            }
            if (fo < NOUT) {
#pragma unroll
                for (int i = 0; i < 4; ++i)
                    preds[(fMt * 16 + q * 4 + i) * PRED_LD + fo] = acc[i];
            }
        }
        LGKM0(); BAR();   // BAR4: preds visible

        // ---- softmax/log_softmax + argmax (first-index) + store ----
        {
            int r = tid >> 4; int l16 = tid & 15; int c0 = l16 * 2;
            float v0 = preds[r * PRED_LD + c0];
            float v1 = preds[r * PRED_LD + c0 + 1];
            float bv; int bi;
            if (v0 >= v1) { bv = v0; bi = c0; } else { bv = v1; bi = c0 + 1; }
#pragma unroll
            for (int d = 1; d < 16; d <<= 1) {
                float ov = __shfl_xor(bv, d);
                int   oi = __shfl_xor(bi, d);
                if (ov > bv || (ov == bv && oi < bi)) { bv = ov; bi = oi; }
            }
            float e0 = __expf(v0 - bv), e1 = __expf(v1 - bv);
            float s = e0 + e1;
#pragma unroll
            for (int d = 1; d < 16; d <<= 1) s += __shfl_xor(s, d);
            float ls = __logf(s);
            float inv = 1.0f / s;
            size_t base = ((size_t)(row0 + r) * NSTEP + t) * NOUT;
            lp[base + c0]     = v0 - bv - ls;
            lp[base + c0 + 1] = v1 - bv - ls;
            pp[base + c0]     = e0 * inv;
            pp[base + c0 + 1] = e1 * inv;
            if (l16 == 0) {
                acts[r] = bi;
                lp[base + 32] = preds[r * PRED_LD + 32];  // raw duration logit stash
            }
        }
        LGKM0(); BAR();   // BAR5: acts visible for next step's gather
    }
#undef LDB
#undef LGKM0
#undef BAR
#undef MFMA
}

// ---------------- duration softmax over time ----------------
__global__ void dur_kernel(float* __restrict__ out) {
    int wid  = threadIdx.x >> 6;
    int lane = threadIdx.x & 63;
    int row  = blockIdx.x * 4 + wid;
    float* lp = out;
    float* pp = out + LOGP_ELEMS;
    size_t base = (size_t)row * NSTEP * NOUT + 32;

    float v[4]; float m = -1e30f;
#pragma unroll
    for (int i = 0; i < 4; ++i) {
        v[i] = lp[base + (size_t)(lane * 4 + i) * NOUT];
        m = fmaxf(m, v[i]);
    }
#pragma unroll
    for (int d = 1; d < 64; d <<= 1) m = fmaxf(m, __shfl_xor(m, d));
    float e[4]; float s = 0.0f;
#pragma unroll
    for (int i = 0; i < 4; ++i) { e[i] = __expf(v[i] - m); s += e[i]; }
#pragma unroll
    for (int d = 1; d < 64; d <<= 1) s += __shfl_xor(s, d);
    float inv = 1.0f / s;
#pragma unroll
    for (int i = 0; i < 4; ++i) {
        size_t idx = base + (size_t)(lane * 4 + i) * NOUT;
        float dv = e[i] * inv;
        lp[idx] = dv;
        pp[idx] = dv;
    }
}

extern "C" void kernel_launch(void* const* d_in, const int* in_sizes, int n_in,
                              void* d_out, int out_size, void* d_ws, size_t ws_size,
                              hipStream_t stream) {
    const float* hid  = (const float*)d_in[1];
    const float* emb  = (const float*)d_in[2];
    const float* wih0 = (const float*)d_in[3];
    const float* whh0 = (const float*)d_in[4];
    const float* bih0 = (const float*)d_in[5];
    const float* bhh0 = (const float*)d_in[6];
    const float* wih1 = (const float*)d_in[7];
    const float* whh1 = (const float*)d_in[8];
    const float* bih1 = (const float*)d_in[9];
    const float* bhh1 = (const float*)d_in[10];
    const float* fcw  = (const float*)d_in[11];
    const float* fcb  = (const float*)d_in[12];

    char*  ws = (char*)d_ws;
    half8* WP = (half8*)ws;                               // WP_BYTES + FP_BYTES
    float* T1 = (float*)(ws + WP_BYTES + FP_BYTES);       // 33*384 f32

    prep_kernel<<<32, 384, 0, stream>>>(emb, wih0, bih0, T1);
    prep_pack<<<75, 256, 0, stream>>>(whh0, wih1, whh1, fcw, WP);

    decoder_kernel<<<NBLK, NTHR, 0, stream>>>(
        hid, T1, ws, bhh0, bih1, bhh1, fcb, (float*)d_out);

    dur_kernel<<<BROWS / 4, 256, 0, stream>>>((float*)d_out);
}

// Round 11
// 3455.936 us; speedup vs baseline: 1.0616x; 1.0616x over previous
//
#include <hip/hip_runtime.h>

#define HDIM  128
#define G3    384
#define RPB   32
#define NTHR  512
#define NSTEP 256
#define NOUT  33
#define BROWS 8192
#define NBLK  (BROWS / RPB)      // 256 blocks -> 1 per CU
#define LOGP_ELEMS 69206016LL    // 8192*256*33
#define PRED_LD 34

typedef _Float16 half8 __attribute__((ext_vector_type(8)));
typedef float    f32x4 __attribute__((ext_vector_type(4)));

// ---------------- LDS byte layout (135552 B, 1 block/CU) ----------------
#define HS0_OFF   0              // h0 splits: [32][256B] swz, split1 at +8192  (16384)
#define HS1_OFF   16384          //                                             (16384)
#define BST_OFF   32768          // ring: 8 waves x 12 slots x 1024 B          (98304)
#define PRED_OFF  131072         // preds [32][34] f32                          (4352)
#define ACTS_OFF  135424         // acts [32] int                                (128)
#define LDS_BYTES 135552

// ---------------- ws layout ----------------
#define WP_BYTES  294912         // 3 mats x 24 nt x 4 kc x 1024 B (single split)
#define FP_BYTES  24576          // fc: 3 nt x 4 kc x 2 s x 1024 B

__device__ __forceinline__ float sigf(float x) { return 1.0f / (1.0f + __expf(-x)); }
__device__ __forceinline__ float tanh_fast(float x) { return 1.0f - 2.0f / (__expf(2.0f*x) + 1.0f); }

// ---------------- prep: gi0 tables (fp32) ----------------
__global__ void prep_kernel(const float* __restrict__ emb, const float* __restrict__ wih0,
                            const float* __restrict__ bih0, float* __restrict__ T1,
                            float* __restrict__ T0) {
    int a = blockIdx.x;          // 0..31
    int g = threadIdx.x;         // 0..383
    const float* e = emb + a * 127;
    const float* w = wih0 + g * HDIM;
    float s = bih0[g];
    for (int k = 0; k < 127; ++k) s += e[k] * w[k];
    T1[a * G3 + g] = s + w[127];
    if (a == 0) T0[g] = s;
}

// ---------------- prep: pack weights (fp16 single split) + fc (2-split) ----------------
// lane holds B[g = nt*16 + (lane&15)][k = kc*32 + (lane>>4)*8 + e]
__global__ void prep_pack(const float* __restrict__ whh0, const float* __restrict__ wih1,
                          const float* __restrict__ whh1, const float* __restrict__ fcw,
                          half8* __restrict__ WP) {
    int b = blockIdx.x;            // 0..74 : 0-71 weight tiles, 72-74 fc
    int tid  = threadIdx.x;        // 256
    int lane = tid & 63;
    int kc   = tid >> 6;
    bool isfc = (b >= 72);
    if (!isfc) {
        int mat = b / 24, nt = b % 24;
        const float* W = (mat == 0) ? whh0 : (mat == 1) ? wih1 : whh1;
        int g = nt * 16 + (lane & 15);
        int k = kc * 32 + (lane >> 4) * 8;
        half8 v1;
#pragma unroll
        for (int e = 0; e < 8; ++e) v1[e] = (_Float16)W[g * HDIM + k + e];
        WP[(size_t)(((mat * 24 + nt) * 4 + kc)) * 64 + lane] = v1;
    } else {
        int nt = b - 72;
        int g = nt * 16 + (lane & 15);
        int k = kc * 32 + (lane >> 4) * 8;
        half8 v1, v2;
#pragma unroll
        for (int e = 0; e < 8; ++e) {
            float x = (g >= NOUT) ? 0.0f : fcw[g * HDIM + k + e];
            _Float16 s1 = (_Float16)x;
            v1[e] = s1; v2[e] = (_Float16)(x - (float)s1);
        }
        size_t base = (size_t)(WP_BYTES / 1024 + (nt * 4 + kc) * 2) * 64 + lane;
        WP[base]      = v1;
        WP[base + 64] = v2;
    }
}

// ---------------- main decoder: deep-ring streamed fp16 weights ----------------
__launch_bounds__(NTHR, 2)
__global__ void decoder_kernel(const float* __restrict__ hid,
                               const float* __restrict__ T1, const float* __restrict__ T0,
                               const char* __restrict__ Bpg,
                               const float* __restrict__ bhh0,
                               const float* __restrict__ bih1, const float* __restrict__ bhh1,
                               const float* __restrict__ fcb,
                               float* __restrict__ out) {
    extern __shared__ char smraw[];
    char*  hs0   = smraw + HS0_OFF;
    char*  hs1   = smraw + HS1_OFF;
    char*  bst   = smraw + BST_OFF;
    float* preds = (float*)(smraw + PRED_OFF);
    int*   acts  = (int*)(smraw + ACTS_OFF);

    const int tid  = threadIdx.x;
    const int row0 = blockIdx.x * RPB;
    float* lp = out;
    float* pp = out + LOGP_ELEMS;

    const int lane  = tid & 63;
    const int w     = tid >> 6;      // wave 0..7
    const int col   = lane & 15;
    const int q     = lane >> 4;
    const int akoff = q * 16;        // A-frag byte offset within 64B k-chunk
    const int j     = w * 16 + col;  // gate/hidden column owned by this lane
    char* const mybuf = bst + (size_t)w * 12288;   // 12 slots x 1024 B

    // hoisted per-lane biases
    const float bG0 = bhh0[j],       bG1 = bhh0[128 + j], bG2 = bhh0[256 + j];
    const float bH0 = bhh1[j],       bH1 = bhh1[128 + j], bH2 = bhh1[256 + j];
    const float bI0 = bih1[j],       bI1 = bih1[128 + j], bI2 = bih1[256 + j];

    // fc weights -> 16 VGPR (2-split); wave (fMt = w/3, fnt = w%3), waves 0-5 active
    const int fnt = w % 3, fMt = (w / 3) & 1;
    const int fo  = fnt * 16 + col;
    const float fbias = (fo < NOUT) ? fcb[fo] : 0.0f;
    half8 fcr[4][2];
#pragma unroll
    for (int kc = 0; kc < 4; ++kc)
#pragma unroll
        for (int s = 0; s < 2; ++s)
            fcr[kc][s] = *(const half8*)(Bpg + WP_BYTES +
                (size_t)(((fnt * 4 + kc) * 2 + s) * 1024) + lane * 16);

    // ---- init h0/h1 -> VGPRs + fp16 2-splits to LDS ----
    float h0v[2][4], h1v[2][4];
#pragma unroll
    for (int Mt = 0; Mt < 2; ++Mt)
#pragma unroll
        for (int i = 0; i < 4; ++i) {
            int row = Mt * 16 + q * 4 + i;
            float v0 = hid[(size_t)(row0 + row) * HDIM + j];
            float v1 = hid[(size_t)BROWS * HDIM + (size_t)(row0 + row) * HDIM + j];
            h0v[Mt][i] = v0; h1v[Mt][i] = v1;
            int off = (row * 256 + j * 2) ^ ((row & 7) << 4);
            _Float16 s1 = (_Float16)v0, s2 = (_Float16)(v0 - (float)s1);
            *(_Float16*)(hs0 + off) = s1;
            *(_Float16*)(hs0 + 8192 + off) = s2;
            s1 = (_Float16)v1; s2 = (_Float16)(v1 - (float)s1);
            *(_Float16*)(hs1 + off) = s1;
            *(_Float16*)(hs1 + 8192 + off) = s2;
        }
    asm volatile("s_waitcnt lgkmcnt(0)" ::: "memory");
    __builtin_amdgcn_s_barrier();

#define LGKM0() asm volatile("s_waitcnt lgkmcnt(0)" ::: "memory")
#define VMW()   asm volatile("s_waitcnt vmcnt(10)" ::: "memory")
#define BAR()   __builtin_amdgcn_s_barrier()
#define MFMA(a, b, c) __builtin_amdgcn_mfma_f32_16x16x32_f16((a), (b), (c), 0, 0, 0)

    // per-step chunk c in [0,36): c<12 -> mat0 (gh0), c<24 -> mat2 (gh1), else mat1 (gi1)
    // within a phase: p = c%12, kc = p/3, ty = p%3; nt = ty*8 + w; tile = 1024 B.
    // ring slot = c % 12 (36 % 12 == 0 -> step-invariant).
    // stage-ahead 10 < depth-1: STAGE(C+10) writes slot (C-2)%12, giving a full
    // chunk of slack after that slot's ds_read (overwrite-hazard hardening).
#define STAGE(C_) do {                                                            \
        int cm_  = (C_) % 36;                                                     \
        int mat_ = (cm_ < 12) ? 0 : ((cm_ < 24) ? 2 : 1);                         \
        int p_   = cm_ % 12;                                                      \
        int kc_  = p_ / 3, ty_ = p_ % 3;                                          \
        char* dst_ = mybuf + (size_t)((C_) % 12) * 1024;                          \
        const char* src_ = Bpg + (size_t)(((mat_ * 24 + (ty_ * 8 + w)) * 4 + kc_) * 1024) + lane * 16; \
        __builtin_amdgcn_global_load_lds((const unsigned int*)src_,               \
                                         (unsigned int*)dst_, 16, 0, 0);          \
    } while (0)

#define CHUNK(C_, A1_, A2_, ACC0_, ACC1_) do {                                    \
        STAGE((C_) + 10);                                                         \
        VMW();                                                                    \
        half8 b_ = *(const half8*)(mybuf + (size_t)((C_) % 12) * 1024 + lane * 16);\
        ACC0_ = MFMA(A1_[0], b_, ACC0_);                                          \
        ACC0_ = MFMA(A2_[0], b_, ACC0_);                                          \
        ACC1_ = MFMA(A1_[1], b_, ACC1_);                                          \
        ACC1_ = MFMA(A2_[1], b_, ACC1_);                                          \
    } while (0)

    // one kc-group: hoist 4 A-frag reads, run the 3 ty-chunks
#define KC3(BASE_, KC_, HS_, ACC_) do {                                           \
        half8 a1_[2], a2_[2];                                                     \
        _Pragma("unroll")                                                         \
        for (int Mt_ = 0; Mt_ < 2; ++Mt_) {                                       \
            int row_ = Mt_ * 16 + col;                                            \
            int off_ = (row_ * 256 + (KC_) * 64 + akoff) ^ ((row_ & 7) << 4);     \
            a1_[Mt_] = *(const half8*)((HS_) + off_);                             \
            a2_[Mt_] = *(const half8*)((HS_) + 8192 + off_);                      \
        }                                                                         \
        CHUNK((BASE_) + (KC_) * 3 + 0, a1_, a2_, ACC_[0][0], ACC_[0][1]);         \
        CHUNK((BASE_) + (KC_) * 3 + 1, a1_, a2_, ACC_[1][0], ACC_[1][1]);         \
        CHUNK((BASE_) + (KC_) * 3 + 2, a1_, a2_, ACC_[2][0], ACC_[2][1]);         \
    } while (0)

    // prologue: stage chunks 0..9
    STAGE(0); STAGE(1); STAGE(2); STAGE(3); STAGE(4);
    STAGE(5); STAGE(6); STAGE(7); STAGE(8); STAGE(9);

#pragma unroll 1
    for (int t = 0; t < NSTEP; ++t) {
        // ---- T-table gather (acts from prev step; latency hides under phase A) ----
        float gi[3][2][4];
        if (t == 0) {
            float g0v = T0[j], g1v = T0[128 + j], g2v = T0[256 + j];
#pragma unroll
            for (int Mt = 0; Mt < 2; ++Mt)
#pragma unroll
                for (int i = 0; i < 4; ++i) {
                    gi[0][Mt][i] = g0v; gi[1][Mt][i] = g1v; gi[2][Mt][i] = g2v;
                }
        } else {
#pragma unroll
            for (int Mt = 0; Mt < 2; ++Mt)
#pragma unroll
                for (int i = 0; i < 4; ++i) {
                    const float* tab = T1 + acts[Mt * 16 + q * 4 + i] * G3;
                    gi[0][Mt][i] = tab[j];
                    gi[1][Mt][i] = tab[128 + j];
                    gi[2][Mt][i] = tab[256 + j];
                }
        }

        // ---- phase A: gh0 (c0-11, A=hs0 old) and gh1 (c12-23, A=hs1 old) ----
        f32x4 g0[3][2], ah[3][2];
        {
            f32x4 v0 = {bG0, bG0, bG0, bG0}, v1 = {bG1, bG1, bG1, bG1}, v2 = {bG2, bG2, bG2, bG2};
            g0[0][0] = v0; g0[0][1] = v0; g0[1][0] = v1; g0[1][1] = v1; g0[2][0] = v2; g0[2][1] = v2;
            f32x4 u0 = {bH0, bH0, bH0, bH0}, u1 = {bH1, bH1, bH1, bH1}, u2 = {bH2, bH2, bH2, bH2};
            ah[0][0] = u0; ah[0][1] = u0; ah[1][0] = u1; ah[1][1] = u1; ah[2][0] = u2; ah[2][1] = u2;
        }
        KC3(0, 0, hs0, g0); KC3(0, 1, hs0, g0); KC3(0, 2, hs0, g0); KC3(0, 3, hs0, g0);
        KC3(12, 0, hs1, ah); KC3(12, 1, hs1, ah); KC3(12, 2, hs1, ah); KC3(12, 3, hs1, ah);
        LGKM0(); BAR();   // BAR1: all hs0/hs1 reads done before rewrites

        // ---- gates0: h0_new -> VGPR + hs0 splits ----
#pragma unroll
        for (int Mt = 0; Mt < 2; ++Mt)
#pragma unroll
            for (int i = 0; i < 4; ++i) {
                float rg = sigf(gi[0][Mt][i] + g0[0][Mt][i]);
                float zg = sigf(gi[1][Mt][i] + g0[1][Mt][i]);
                float ng = tanh_fast(gi[2][Mt][i] + rg * g0[2][Mt][i]);
                float hnew = (1.0f - zg) * ng + zg * h0v[Mt][i];
                h0v[Mt][i] = hnew;
                int row = Mt * 16 + q * 4 + i;
                int off = (row * 256 + j * 2) ^ ((row & 7) << 4);
                _Float16 s1 = (_Float16)hnew, s2 = (_Float16)(hnew - (float)s1);
                *(_Float16*)(hs0 + off) = s1;
                *(_Float16*)(hs0 + 8192 + off) = s2;
            }
        LGKM0(); BAR();   // BAR2: hs0_new visible

        // ---- mat1: gi1 (c24-35, A=hs0_new) ----
        f32x4 ai[3][2];
        {
            f32x4 v0 = {bI0, bI0, bI0, bI0}, v1 = {bI1, bI1, bI1, bI1}, v2 = {bI2, bI2, bI2, bI2};
            ai[0][0] = v0; ai[0][1] = v0; ai[1][0] = v1; ai[1][1] = v1; ai[2][0] = v2; ai[2][1] = v2;
        }
        KC3(24, 0, hs0, ai); KC3(24, 1, hs0, ai); KC3(24, 2, hs0, ai); KC3(24, 3, hs0, ai);

        // ---- gates1: h1_new -> VGPR + hs1 splits (hs1 reads fenced by BAR1) ----
#pragma unroll
        for (int Mt = 0; Mt < 2; ++Mt)
#pragma unroll
            for (int i = 0; i < 4; ++i) {
                float rg = sigf(ai[0][Mt][i] + ah[0][Mt][i]);
                float zg = sigf(ai[1][Mt][i] + ah[1][Mt][i]);
                float ng = tanh_fast(ai[2][Mt][i] + rg * ah[2][Mt][i]);
                float hnew = (1.0f - zg) * ng + zg * h1v[Mt][i];
                h1v[Mt][i] = hnew;
                int row = Mt * 16 + q * 4 + i;
                int off = (row * 256 + j * 2) ^ ((row & 7) << 4);
                _Float16 s1 = (_Float16)hnew, s2 = (_Float16)(hnew - (float)s1);
                *(_Float16*)(hs1 + off) = s1;
                *(_Float16*)(hs1 + 8192 + off) = s2;
            }
        LGKM0(); BAR();   // BAR3: hs1_new visible

        // ---- fc: preds = h1_new.fc_w^T + fc_b (waves 0-5, B in VGPRs) ----
        if (w < 6) {
            f32x4 acc = {fbias, fbias, fbias, fbias};
#pragma unroll
            for (int kc = 0; kc < 4; ++kc) {
                int row = fMt * 16 + col;
                int off = (row * 256 + kc * 64 + akoff) ^ ((row & 7) << 4);
                half8 a1 = *(const half8*)(hs1 + off);
                half8 a2 = *(const half8*)(hs1 + 8192 + off);
                acc = MFMA(a1, fcr[kc][0], acc);
                acc = MFMA(a2, fcr[kc][0], acc);
                acc = MFMA(a1, fcr[kc][1], acc);
            }
            if (fo < NOUT) {
#pragma unroll
                for (int i = 0; i < 4; ++i)
                    preds[(fMt * 16 + q * 4 + i) * PRED_LD + fo] = acc[i];
            }
        }
        LGKM0(); BAR();   // BAR4: preds visible

        // ---- softmax/log_softmax + argmax (first-index) + store (plain stores) ----
        {
            int r = tid >> 4; int l16 = tid & 15; int c0 = l16 * 2;
            float v0 = preds[r * PRED_LD + c0];
            float v1 = preds[r * PRED_LD + c0 + 1];
            float bv; int bi;
            if (v0 >= v1) { bv = v0; bi = c0; } else { bv = v1; bi = c0 + 1; }
#pragma unroll
            for (int d = 1; d < 16; d <<= 1) {
                float ov = __shfl_xor(bv, d);
                int   oi = __shfl_xor(bi, d);
                if (ov > bv || (ov == bv && oi < bi)) { bv = ov; bi = oi; }
            }
            float e0 = __expf(v0 - bv), e1 = __expf(v1 - bv);
            float s = e0 + e1;
#pragma unroll
            for (int d = 1; d < 16; d <<= 1) s += __shfl_xor(s, d);
            float ls = __logf(s);
            float inv = 1.0f / s;
            size_t base = ((size_t)(row0 + r) * NSTEP + t) * NOUT;
            lp[base + c0]     = v0 - bv - ls;
            lp[base + c0 + 1] = v1 - bv - ls;
            pp[base + c0]     = e0 * inv;
            pp[base + c0 + 1] = e1 * inv;
            if (l16 == 0) {
                acts[r] = bi;
                lp[base + 32] = preds[r * PRED_LD + 32];  // raw duration logit stash
            }
        }
        LGKM0(); BAR();   // BAR5: acts visible for next step
    }
#undef STAGE
#undef CHUNK
#undef KC3
#undef LGKM0
#undef VMW
#undef BAR
#undef MFMA
}

// ---------------- duration softmax over time ----------------
__global__ void dur_kernel(float* __restrict__ out) {
    int wid  = threadIdx.x >> 6;
    int lane = threadIdx.x & 63;
    int row  = blockIdx.x * 4 + wid;
    float* lp = out;
    float* pp = out + LOGP_ELEMS;
    size_t base = (size_t)row * NSTEP * NOUT + 32;

    float v[4]; float m = -1e30f;
#pragma unroll
    for (int i = 0; i < 4; ++i) {
        v[i] = lp[base + (size_t)(lane * 4 + i) * NOUT];
        m = fmaxf(m, v[i]);
    }
#pragma unroll
    for (int d = 1; d < 64; d <<= 1) m = fmaxf(m, __shfl_xor(m, d));
    float e[4]; float s = 0.0f;
#pragma unroll
    for (int i = 0; i < 4; ++i) { e[i] = __expf(v[i] - m); s += e[i]; }
#pragma unroll
    for (int d = 1; d < 64; d <<= 1) s += __shfl_xor(s, d);
    float inv = 1.0f / s;
#pragma unroll
    for (int i = 0; i < 4; ++i) {
        size_t idx = base + (size_t)(lane * 4 + i) * NOUT;
        float dv = e[i] * inv;
        lp[idx] = dv;
        pp[idx] = dv;
    }
}

extern "C" void kernel_launch(void* const* d_in, const int* in_sizes, int n_in,
                              void* d_out, int out_size, void* d_ws, size_t ws_size,
                              hipStream_t stream) {
    const float* hid  = (const float*)d_in[1];
    const float* emb  = (const float*)d_in[2];
    const float* wih0 = (const float*)d_in[3];
    const float* whh0 = (const float*)d_in[4];
    const float* bih0 = (const float*)d_in[5];
    const float* bhh0 = (const float*)d_in[6];
    const float* wih1 = (const float*)d_in[7];
    const float* whh1 = (const float*)d_in[8];
    const float* bih1 = (const float*)d_in[9];
    const float* bhh1 = (const float*)d_in[10];
    const float* fcw  = (const float*)d_in[11];
    const float* fcb  = (const float*)d_in[12];

    char*  ws = (char*)d_ws;
    half8* WP = (half8*)ws;                               // WP_BYTES + FP_BYTES
    float* T1 = (float*)(ws + WP_BYTES + FP_BYTES);       // 32*384 f32
    float* T0 = T1 + 32 * G3;                             // 384 f32

    prep_kernel<<<32, 384, 0, stream>>>(emb, wih0, bih0, T1, T0);
    prep_pack<<<75, 256, 0, stream>>>(whh0, wih1, whh1, fcw, WP);

    hipFuncSetAttribute((const void*)decoder_kernel,
                        hipFuncAttributeMaxDynamicSharedMemorySize, LDS_BYTES);
    decoder_kernel<<<NBLK, NTHR, LDS_BYTES, stream>>>(
        hid, T1, T0, ws, bhh0, bih1, bhh1, fcb, (float*)d_out);

    dur_kernel<<<BROWS / 4, 256, 0, stream>>>((float*)d_out);
}